// Round 1
// baseline (814.412 us; speedup 1.0000x reference)
//
#include <hip/hip_runtime.h>

#define EPSV 1e-5f

// Problem constants: B=4 clips, N=8 frames, B2=32, C=128, H=W=64, HW=4096, KS=3
// Workspace layout (floats):
//   k2d  @ 0         : 32*128*4096 = 16777216
//   v    @ 16777216  : 16777216
//   wd   @ 33554432  : 32*96*4096  = 12582912
//   stats@ 46137344  : gnsum[1024] gnsq[1024] gap[512] gnmean[1024] gnrstd[1024] attn[1024]
// total 46142976 floats = 184,571,904 bytes

__device__ __forceinline__ void block_sum_atomic(float val, float* dst) {
    __shared__ float sm[4];
    #pragma unroll
    for (int off = 32; off; off >>= 1) val += __shfl_down(val, off, 64);
    int lane = threadIdx.x & 63, wid = threadIdx.x >> 6;
    if (lane == 0) sm[wid] = val;
    __syncthreads();
    if (threadIdx.x == 0) atomicAdd(dst, sm[0] + sm[1] + sm[2] + sm[3]);
}

// ---- kA: key_embed = ReLU(BN(grouped temporal conv3d)) + gap partial ----
__global__ __launch_bounds__(256) void kA_key(
    const float* __restrict__ x, const float* __restrict__ wk,
    const float* __restrict__ g, const float* __restrict__ bb,
    const float* __restrict__ m, const float* __restrict__ vr,
    float* __restrict__ k2d, float* __restrict__ gap)
{
    int tile = blockIdx.x & 15;
    int o    = (blockIdx.x >> 4) & 127;
    int b2   = blockIdx.x >> 11;
    int hw   = tile * 256 + threadIdx.x;
    int bi = b2 >> 3, ni = b2 & 7;
    int gch = (o >> 5) << 5;                 // group input-channel base
    const float* wko = wk + o * 96;          // [ci*3 + dk]
    float acc = 0.f;
    #pragma unroll
    for (int dk = 0; dk < 3; ++dk) {
        int nf = ni + dk - 1;
        if (nf >= 0 && nf < 8) {
            const float* xp = x + ((bi * 8 + nf) * 128 + gch) * 4096 + hw;
            #pragma unroll
            for (int ci = 0; ci < 32; ++ci)
                acc = fmaf(xp[ci * 4096], wko[ci * 3 + dk], acc);
        }
    }
    float s = g[o] * rsqrtf(vr[o] + EPSV);
    float val = fmaxf(fmaf(acc, s, bb[o] - m[o] * s), 0.f);
    k2d[(b2 * 128 + o) * 4096 + hw] = val;
    block_sum_atomic(val, &gap[bi * 128 + o]);
}

// ---- kB: v = BN(x @ w_1x1) ----
__global__ __launch_bounds__(256) void kB_val(
    const float* __restrict__ x, const float* __restrict__ w,
    const float* __restrict__ g, const float* __restrict__ bb,
    const float* __restrict__ m, const float* __restrict__ vr,
    float* __restrict__ vout)
{
    int oc   = blockIdx.x & 3;
    int tile = (blockIdx.x >> 2) & 15;
    int b2   = blockIdx.x >> 6;
    int hw   = tile * 256 + threadIdx.x;
    const float* xp = x + b2 * 128 * 4096 + hw;
    const float* wp = w + oc * 32 * 128;
    float acc[32];
    #pragma unroll
    for (int i = 0; i < 32; ++i) acc[i] = 0.f;
    for (int c = 0; c < 128; ++c) {
        float xv = xp[c * 4096];
        #pragma unroll
        for (int o8 = 0; o8 < 32; ++o8)
            acc[o8] = fmaf(wp[o8 * 128 + c], xv, acc[o8]);
    }
    #pragma unroll
    for (int o8 = 0; o8 < 32; ++o8) {
        int o = oc * 32 + o8;
        float s = g[o] * rsqrtf(vr[o] + EPSV);
        vout[(b2 * 128 + o) * 4096 + hw] = fmaf(acc[o8], s, bb[o] - m[o] * s);
    }
}

// ---- kC: e = ReLU(BN([x;k2d] @ w_e1)), wd = e @ w_e2 + b_e2, + GN partial sums ----
__global__ __launch_bounds__(256) void kC_wd(
    const float* __restrict__ x, const float* __restrict__ k2d,
    const float* __restrict__ we1,
    const float* __restrict__ eg, const float* __restrict__ eb,
    const float* __restrict__ em, const float* __restrict__ ev,
    const float* __restrict__ we2, const float* __restrict__ be2,
    float* __restrict__ wd, float* __restrict__ gnsum, float* __restrict__ gnsq)
{
    int tid  = threadIdx.x;
    int tile = blockIdx.x & 15;
    int b2   = blockIdx.x >> 4;
    int hw   = tile * 256 + tid;
    const float* xp = x   + b2 * 128 * 4096 + hw;
    const float* kp = k2d + b2 * 128 * 4096 + hw;
    float e[64];
    #pragma unroll
    for (int i = 0; i < 64; ++i) e[i] = 0.f;
    for (int c = 0; c < 128; ++c) {
        float qv = xp[c * 4096];
        #pragma unroll
        for (int eo = 0; eo < 64; ++eo)
            e[eo] = fmaf(we1[eo * 256 + c], qv, e[eo]);
    }
    for (int c = 0; c < 128; ++c) {
        float qv = kp[c * 4096];
        #pragma unroll
        for (int eo = 0; eo < 64; ++eo)
            e[eo] = fmaf(we1[eo * 256 + 128 + c], qv, e[eo]);
    }
    #pragma unroll
    for (int eo = 0; eo < 64; ++eo) {
        float s = eg[eo] * rsqrtf(ev[eo] + EPSV);
        e[eo] = fmaxf(fmaf(e[eo], s, eb[eo] - em[eo] * s), 0.f);
    }
    __shared__ float ssum[32][4], ssq[32][4];
    int lane = tid & 63, wid = tid >> 6;
    float* wdp = wd + b2 * 96 * 4096 + hw;
    for (int c1 = 0; c1 < 32; ++c1) {
        float lsum = 0.f, lsq = 0.f;
        #pragma unroll
        for (int k = 0; k < 3; ++k) {
            int wo = c1 * 3 + k;
            float acc = be2[wo];
            #pragma unroll
            for (int c = 0; c < 64; ++c)
                acc = fmaf(we2[wo * 64 + c], e[c], acc);
            wdp[wo * 4096] = acc;
            lsum += acc; lsq += acc * acc;
        }
        #pragma unroll
        for (int off = 32; off; off >>= 1) {
            lsum += __shfl_down(lsum, off, 64);
            lsq  += __shfl_down(lsq,  off, 64);
        }
        if (lane == 0) { ssum[c1][wid] = lsum; ssq[c1][wid] = lsq; }
    }
    __syncthreads();
    if (tid < 32) {
        float s = ssum[tid][0] + ssum[tid][1] + ssum[tid][2] + ssum[tid][3];
        float q = ssq[tid][0]  + ssq[tid][1]  + ssq[tid][2]  + ssq[tid][3];
        atomicAdd(&gnsum[b2 * 32 + tid], s);
        atomicAdd(&gnsq[b2 * 32 + tid], q);
    }
}

// ---- kC2: finalize GroupNorm stats (1024 groups, 12288 elems each) ----
__global__ __launch_bounds__(256) void kC2_gn(
    const float* __restrict__ gnsum, const float* __restrict__ gnsq,
    float* __restrict__ gnmean, float* __restrict__ gnrstd)
{
    int idx = blockIdx.x * 256 + threadIdx.x;   // grid 4 -> 1024
    const float inv = 1.f / 12288.f;
    float mu  = gnsum[idx] * inv;
    float var = fmaf(gnsq[idx], inv, -mu * mu);
    gnmean[idx] = mu;
    gnrstd[idx] = rsqrtf(fmaxf(var, 0.f) + EPSV);
}

// ---- kD: agg = SiLU(BN2(sum_k GN(wd) * unfold(v))) -> d_out, + gap partial ----
__global__ __launch_bounds__(256) void kD_agg(
    const float* __restrict__ wd, const float* __restrict__ v,
    const float* __restrict__ gnmean, const float* __restrict__ gnrstd,
    const float* __restrict__ gng, const float* __restrict__ gnb,
    const float* __restrict__ g, const float* __restrict__ bb,
    const float* __restrict__ m, const float* __restrict__ vr,
    float* __restrict__ out, float* __restrict__ gap)
{
    int tile = blockIdx.x & 15;
    int c    = (blockIdx.x >> 4) & 127;
    int b2   = blockIdx.x >> 11;
    int hw   = tile * 256 + threadIdx.x;
    int bi = b2 >> 3, ni = b2 & 7;
    int c1 = c >> 2;
    float mu = gnmean[b2 * 32 + c1], rs = gnrstd[b2 * 32 + c1];
    float acc = 0.f;
    #pragma unroll
    for (int k = 0; k < 3; ++k) {
        int nf = ni + k - 1;
        if (nf >= 0 && nf < 8) {
            int wo = c1 * 3 + k;
            float wv = wd[(b2 * 96 + wo) * 4096 + hw];
            float wn = fmaf((wv - mu) * rs, gng[wo], gnb[wo]);
            float vvv = v[((bi * 8 + nf) * 128 + c) * 4096 + hw];
            acc = fmaf(wn, vvv, acc);
        }
    }
    float s = g[c] * rsqrtf(vr[c] + EPSV);
    float y = fmaf(acc, s, bb[c] - m[c] * s);
    float fy = y / (1.f + __expf(-y));
    out[(b2 * 128 + c) * 4096 + hw] = fy;
    block_sum_atomic(fy, &gap[bi * 128 + c]);
}

// ---- kE: SE head: a = ReLU(BNvec(gap/32768 @ w_se1^T + b1)); attn = softmax pairs ----
__global__ __launch_bounds__(256) void kE_attn(
    const float* __restrict__ gap,
    const float* __restrict__ w1, const float* __restrict__ b1,
    const float* __restrict__ g, const float* __restrict__ bb,
    const float* __restrict__ m, const float* __restrict__ vr,
    const float* __restrict__ w2, const float* __restrict__ b2v,
    float* __restrict__ attn)
{
    __shared__ float a_s[4][128];
    int tid = threadIdx.x;
    if (tid < 128) {
        float s = g[tid] * rsqrtf(vr[tid] + EPSV);
        float t = bb[tid] - m[tid] * s;
        for (int bi = 0; bi < 4; ++bi) {
            float acc = b1[tid];
            for (int c = 0; c < 128; ++c)
                acc = fmaf(gap[bi * 128 + c] * (1.f / 32768.f), w1[tid * 128 + c], acc);
            a_s[bi][tid] = fmaxf(fmaf(acc, s, t), 0.f);
        }
    }
    __syncthreads();
    if (tid < 128) {
        for (int bi = 0; bi < 4; ++bi) {
            float l0 = b2v[tid * 2], l1 = b2v[tid * 2 + 1];
            for (int j = 0; j < 128; ++j) {
                float av = a_s[bi][j];
                l0 = fmaf(av, w2[(tid * 2) * 128 + j], l0);
                l1 = fmaf(av, w2[(tid * 2 + 1) * 128 + j], l1);
            }
            float mx = fmaxf(l0, l1);
            float e0 = __expf(l0 - mx), e1 = __expf(l1 - mx);
            float inv = 1.f / (e0 + e1);
            attn[bi * 256 + tid * 2]     = e0 * inv;
            attn[bi * 256 + tid * 2 + 1] = e1 * inv;
        }
    }
}

// ---- kF: out = attn0*agg + attn1*k2d (in-place on d_out) ----
__global__ __launch_bounds__(256) void kF_out(
    float* __restrict__ out, const float* __restrict__ k2d,
    const float* __restrict__ attn)
{
    int tile = blockIdx.x & 15;
    int c    = (blockIdx.x >> 4) & 127;
    int b2   = blockIdx.x >> 11;
    int bi   = b2 >> 3;
    float a0 = attn[bi * 256 + c * 2];
    float a1 = attn[bi * 256 + c * 2 + 1];
    int idx = (b2 * 128 + c) * 4096 + tile * 256 + threadIdx.x;
    out[idx] = fmaf(a0, out[idx], a1 * k2d[idx]);
}

extern "C" void kernel_launch(void* const* d_in, const int* in_sizes, int n_in,
                              void* d_out, int out_size, void* d_ws, size_t ws_size,
                              hipStream_t stream)
{
    const float* x      = (const float*)d_in[0];
    const float* w_key  = (const float*)d_in[1];
    const float* bnk_g  = (const float*)d_in[2];
    const float* bnk_b  = (const float*)d_in[3];
    const float* bnk_m  = (const float*)d_in[4];
    const float* bnk_v  = (const float*)d_in[5];
    const float* w_e1   = (const float*)d_in[6];
    const float* bne_g  = (const float*)d_in[7];
    const float* bne_b  = (const float*)d_in[8];
    const float* bne_m  = (const float*)d_in[9];
    const float* bne_v  = (const float*)d_in[10];
    const float* w_e2   = (const float*)d_in[11];
    const float* b_e2   = (const float*)d_in[12];
    const float* gn_g   = (const float*)d_in[13];
    const float* gn_b   = (const float*)d_in[14];
    const float* w_1x1  = (const float*)d_in[15];
    const float* bn1_g  = (const float*)d_in[16];
    const float* bn1_b  = (const float*)d_in[17];
    const float* bn1_m  = (const float*)d_in[18];
    const float* bn1_v  = (const float*)d_in[19];
    const float* bn2_g  = (const float*)d_in[20];
    const float* bn2_b  = (const float*)d_in[21];
    const float* bn2_m  = (const float*)d_in[22];
    const float* bn2_v  = (const float*)d_in[23];
    const float* w_se1  = (const float*)d_in[24];
    const float* b_se1  = (const float*)d_in[25];
    const float* bnse_g = (const float*)d_in[26];
    const float* bnse_b = (const float*)d_in[27];
    const float* bnse_m = (const float*)d_in[28];
    const float* bnse_v = (const float*)d_in[29];
    const float* w_se2  = (const float*)d_in[30];
    const float* b_se2  = (const float*)d_in[31];

    float* ws    = (float*)d_ws;
    float* k2d   = ws;
    float* v     = ws + 16777216;
    float* wd    = ws + 33554432;
    float* st    = ws + 46137344;
    float* gnsum  = st;
    float* gnsq   = st + 1024;
    float* gap    = st + 2048;
    float* gnmean = st + 2560;
    float* gnrstd = st + 3584;
    float* attn   = st + 4608;

    // zero the accumulators (gnsum, gnsq, gap are contiguous: 2560 floats)
    hipMemsetAsync(gnsum, 0, 2560 * sizeof(float), stream);

    kA_key<<<32 * 128 * 16, 256, 0, stream>>>(x, w_key, bnk_g, bnk_b, bnk_m, bnk_v, k2d, gap);
    kB_val<<<32 * 16 * 4, 256, 0, stream>>>(x, w_1x1, bn1_g, bn1_b, bn1_m, bn1_v, v);
    kC_wd<<<32 * 16, 256, 0, stream>>>(x, k2d, w_e1, bne_g, bne_b, bne_m, bne_v,
                                       w_e2, b_e2, wd, gnsum, gnsq);
    kC2_gn<<<4, 256, 0, stream>>>(gnsum, gnsq, gnmean, gnrstd);
    kD_agg<<<32 * 128 * 16, 256, 0, stream>>>(wd, v, gnmean, gnrstd, gn_g, gn_b,
                                              bn2_g, bn2_b, bn2_m, bn2_v,
                                              (float*)d_out, gap);
    kE_attn<<<1, 256, 0, stream>>>(gap, w_se1, b_se1, bnse_g, bnse_b, bnse_m, bnse_v,
                                   w_se2, b_se2, attn);
    kF_out<<<32 * 128 * 16, 256, 0, stream>>>((float*)d_out, k2d, attn);
}

// Round 2
// 689.272 us; speedup vs baseline: 1.1816x; 1.1816x over previous
//
#include <hip/hip_runtime.h>

#define EPSV 1e-5f

// Problem constants: B=4 clips, N=8 frames, B2=32, C=128, H=W=64, HW=4096, KS=3
// Workspace layout (floats):
//   k2d  @ 0         : 32*128*4096 = 16777216
//   v    @ 16777216  : 16777216
//   wd   @ 33554432  : 32*96*4096  = 12582912
//   stats@ 46137344  : gnsum[1024] gnsq[1024] gap[512] gnmean[1024] gnrstd[1024] attn[1024]

__device__ __forceinline__ void block_sum_atomic(float val, float* dst) {
    __shared__ float sm[4];
    #pragma unroll
    for (int off = 32; off; off >>= 1) val += __shfl_down(val, off, 64);
    int lane = threadIdx.x & 63, wid = threadIdx.x >> 6;
    if (lane == 0) sm[wid] = val;
    __syncthreads();
    if (threadIdx.x == 0) atomicAdd(dst, sm[0] + sm[1] + sm[2] + sm[3]);
}

// ---- kA: key_embed = ReLU(BN(grouped temporal conv3d)) + gap partial ----
// One block = one (b2, group, hw-tile): 32 output channels in registers.
__global__ __launch_bounds__(256) void kA_key(
    const float* __restrict__ x, const float* __restrict__ wk,
    const float* __restrict__ g, const float* __restrict__ bb,
    const float* __restrict__ m, const float* __restrict__ vr,
    float* __restrict__ k2d, float* __restrict__ gap)
{
    int tile = blockIdx.x & 15;
    int grp  = (blockIdx.x >> 4) & 3;
    int b2   = blockIdx.x >> 6;
    int hw   = tile * 256 + threadIdx.x;
    int bi = b2 >> 3, ni = b2 & 7;
    int gch = grp * 32;
    float acc[32];
    #pragma unroll
    for (int i = 0; i < 32; ++i) acc[i] = 0.f;
    #pragma unroll
    for (int dk = 0; dk < 3; ++dk) {
        int nf = ni + dk - 1;
        if (nf >= 0 && nf < 8) {
            const float* xp = x + ((bi * 8 + nf) * 128 + gch) * 4096 + hw;
            const float* wp = wk + gch * 96 + dk;   // w[(gch+o8)*96 + ci*3 + dk]
            for (int ci = 0; ci < 32; ++ci) {
                float xv = xp[ci * 4096];
                #pragma unroll
                for (int o8 = 0; o8 < 32; ++o8)
                    acc[o8] = fmaf(xv, wp[o8 * 96 + ci * 3], acc[o8]);
            }
        }
    }
    __shared__ float ssum[32][4];
    int lane = threadIdx.x & 63, wid = threadIdx.x >> 6;
    #pragma unroll
    for (int o8 = 0; o8 < 32; ++o8) {
        int o = gch + o8;
        float s = g[o] * rsqrtf(vr[o] + EPSV);
        float val = fmaxf(fmaf(acc[o8], s, bb[o] - m[o] * s), 0.f);
        k2d[(b2 * 128 + o) * 4096 + hw] = val;
        #pragma unroll
        for (int off = 32; off; off >>= 1) val += __shfl_down(val, off, 64);
        if (lane == 0) ssum[o8][wid] = val;
    }
    __syncthreads();
    if (threadIdx.x < 32) {
        float* sr = ssum[threadIdx.x];
        atomicAdd(&gap[bi * 128 + gch + threadIdx.x], sr[0] + sr[1] + sr[2] + sr[3]);
    }
}

// ---- kB: v = BN(x @ w_1x1) ----
__global__ __launch_bounds__(256) void kB_val(
    const float* __restrict__ x, const float* __restrict__ w,
    const float* __restrict__ g, const float* __restrict__ bb,
    const float* __restrict__ m, const float* __restrict__ vr,
    float* __restrict__ vout)
{
    int oc   = blockIdx.x & 3;
    int tile = (blockIdx.x >> 2) & 15;
    int b2   = blockIdx.x >> 6;
    int hw   = tile * 256 + threadIdx.x;
    const float* xp = x + b2 * 128 * 4096 + hw;
    const float* wp = w + oc * 32 * 128;
    float acc[32];
    #pragma unroll
    for (int i = 0; i < 32; ++i) acc[i] = 0.f;
    for (int c = 0; c < 128; ++c) {
        float xv = xp[c * 4096];
        #pragma unroll
        for (int o8 = 0; o8 < 32; ++o8)
            acc[o8] = fmaf(wp[o8 * 128 + c], xv, acc[o8]);
    }
    #pragma unroll
    for (int o8 = 0; o8 < 32; ++o8) {
        int o = oc * 32 + o8;
        float s = g[o] * rsqrtf(vr[o] + EPSV);
        vout[(b2 * 128 + o) * 4096 + hw] = fmaf(acc[o8], s, bb[o] - m[o] * s);
    }
}

// ---- kC: e = ReLU(BN([x;k2d] @ w_e1)), wd = e @ w_e2 + b_e2, + GN partial sums ----
__global__ __launch_bounds__(256) void kC_wd(
    const float* __restrict__ x, const float* __restrict__ k2d,
    const float* __restrict__ we1,
    const float* __restrict__ eg, const float* __restrict__ eb,
    const float* __restrict__ em, const float* __restrict__ ev,
    const float* __restrict__ we2, const float* __restrict__ be2,
    float* __restrict__ wd, float* __restrict__ gnsum, float* __restrict__ gnsq)
{
    int tid  = threadIdx.x;
    int tile = blockIdx.x & 15;
    int b2   = blockIdx.x >> 4;
    int hw   = tile * 256 + tid;
    const float* xp = x   + b2 * 128 * 4096 + hw;
    const float* kp = k2d + b2 * 128 * 4096 + hw;
    float e[64];
    #pragma unroll
    for (int i = 0; i < 64; ++i) e[i] = 0.f;
    for (int c = 0; c < 128; ++c) {
        float qv = xp[c * 4096];
        #pragma unroll
        for (int eo = 0; eo < 64; ++eo)
            e[eo] = fmaf(we1[eo * 256 + c], qv, e[eo]);
    }
    for (int c = 0; c < 128; ++c) {
        float qv = kp[c * 4096];
        #pragma unroll
        for (int eo = 0; eo < 64; ++eo)
            e[eo] = fmaf(we1[eo * 256 + 128 + c], qv, e[eo]);
    }
    #pragma unroll
    for (int eo = 0; eo < 64; ++eo) {
        float s = eg[eo] * rsqrtf(ev[eo] + EPSV);
        e[eo] = fmaxf(fmaf(e[eo], s, eb[eo] - em[eo] * s), 0.f);
    }
    __shared__ float ssum[32][4], ssq[32][4];
    int lane = tid & 63, wid = tid >> 6;
    float* wdp = wd + b2 * 96 * 4096 + hw;
    for (int c1 = 0; c1 < 32; ++c1) {
        float lsum = 0.f, lsq = 0.f;
        #pragma unroll
        for (int k = 0; k < 3; ++k) {
            int wo = c1 * 3 + k;
            float acc = be2[wo];
            #pragma unroll
            for (int c = 0; c < 64; ++c)
                acc = fmaf(we2[wo * 64 + c], e[c], acc);
            wdp[wo * 4096] = acc;
            lsum += acc; lsq += acc * acc;
        }
        #pragma unroll
        for (int off = 32; off; off >>= 1) {
            lsum += __shfl_down(lsum, off, 64);
            lsq  += __shfl_down(lsq,  off, 64);
        }
        if (lane == 0) { ssum[c1][wid] = lsum; ssq[c1][wid] = lsq; }
    }
    __syncthreads();
    if (tid < 32) {
        float s = ssum[tid][0] + ssum[tid][1] + ssum[tid][2] + ssum[tid][3];
        float q = ssq[tid][0]  + ssq[tid][1]  + ssq[tid][2]  + ssq[tid][3];
        atomicAdd(&gnsum[b2 * 32 + tid], s);
        atomicAdd(&gnsq[b2 * 32 + tid], q);
    }
}

// ---- kC2: finalize GroupNorm stats (1024 groups, 12288 elems each) ----
__global__ __launch_bounds__(256) void kC2_gn(
    const float* __restrict__ gnsum, const float* __restrict__ gnsq,
    float* __restrict__ gnmean, float* __restrict__ gnrstd)
{
    int idx = blockIdx.x * 256 + threadIdx.x;
    const float inv = 1.f / 12288.f;
    float mu  = gnsum[idx] * inv;
    float var = fmaf(gnsq[idx], inv, -mu * mu);
    gnmean[idx] = mu;
    gnrstd[idx] = rsqrtf(fmaxf(var, 0.f) + EPSV);
}

// ---- kD: agg = SiLU(BN2(sum_k GN(wd) * unfold(v))) -> d_out, + gap partial ----
__global__ __launch_bounds__(256) void kD_agg(
    const float* __restrict__ wd, const float* __restrict__ v,
    const float* __restrict__ gnmean, const float* __restrict__ gnrstd,
    const float* __restrict__ gng, const float* __restrict__ gnb,
    const float* __restrict__ g, const float* __restrict__ bb,
    const float* __restrict__ m, const float* __restrict__ vr,
    float* __restrict__ out, float* __restrict__ gap)
{
    int tile = blockIdx.x & 15;
    int c    = (blockIdx.x >> 4) & 127;
    int b2   = blockIdx.x >> 11;
    int hw   = tile * 256 + threadIdx.x;
    int bi = b2 >> 3, ni = b2 & 7;
    int c1 = c >> 2;
    float mu = gnmean[b2 * 32 + c1], rs = gnrstd[b2 * 32 + c1];
    float acc = 0.f;
    #pragma unroll
    for (int k = 0; k < 3; ++k) {
        int nf = ni + k - 1;
        if (nf >= 0 && nf < 8) {
            int wo = c1 * 3 + k;
            float wv = wd[(b2 * 96 + wo) * 4096 + hw];
            float wn = fmaf((wv - mu) * rs, gng[wo], gnb[wo]);
            float vvv = v[((bi * 8 + nf) * 128 + c) * 4096 + hw];
            acc = fmaf(wn, vvv, acc);
        }
    }
    float s = g[c] * rsqrtf(vr[c] + EPSV);
    float y = fmaf(acc, s, bb[c] - m[c] * s);
    float fy = y / (1.f + __expf(-y));
    out[(b2 * 128 + c) * 4096 + hw] = fy;
    block_sum_atomic(fy, &gap[bi * 128 + c]);
}

// ---- kE: SE head ----
__global__ __launch_bounds__(256) void kE_attn(
    const float* __restrict__ gap,
    const float* __restrict__ w1, const float* __restrict__ b1,
    const float* __restrict__ g, const float* __restrict__ bb,
    const float* __restrict__ m, const float* __restrict__ vr,
    const float* __restrict__ w2, const float* __restrict__ b2v,
    float* __restrict__ attn)
{
    __shared__ float a_s[4][128];
    int tid = threadIdx.x;
    if (tid < 128) {
        float s = g[tid] * rsqrtf(vr[tid] + EPSV);
        float t = bb[tid] - m[tid] * s;
        for (int bi = 0; bi < 4; ++bi) {
            float acc = b1[tid];
            for (int c = 0; c < 128; ++c)
                acc = fmaf(gap[bi * 128 + c] * (1.f / 32768.f), w1[tid * 128 + c], acc);
            a_s[bi][tid] = fmaxf(fmaf(acc, s, t), 0.f);
        }
    }
    __syncthreads();
    if (tid < 128) {
        for (int bi = 0; bi < 4; ++bi) {
            float l0 = b2v[tid * 2], l1 = b2v[tid * 2 + 1];
            for (int j = 0; j < 128; ++j) {
                float av = a_s[bi][j];
                l0 = fmaf(av, w2[(tid * 2) * 128 + j], l0);
                l1 = fmaf(av, w2[(tid * 2 + 1) * 128 + j], l1);
            }
            float mx = fmaxf(l0, l1);
            float e0 = __expf(l0 - mx), e1 = __expf(l1 - mx);
            float inv = 1.f / (e0 + e1);
            attn[bi * 256 + tid * 2]     = e0 * inv;
            attn[bi * 256 + tid * 2 + 1] = e1 * inv;
        }
    }
}

// ---- kF: out = attn0*agg + attn1*k2d (in-place on d_out) ----
__global__ __launch_bounds__(256) void kF_out(
    float* __restrict__ out, const float* __restrict__ k2d,
    const float* __restrict__ attn)
{
    int tile = blockIdx.x & 15;
    int c    = (blockIdx.x >> 4) & 127;
    int b2   = blockIdx.x >> 11;
    int bi   = b2 >> 3;
    float a0 = attn[bi * 256 + c * 2];
    float a1 = attn[bi * 256 + c * 2 + 1];
    int idx = (b2 * 128 + c) * 4096 + tile * 256 + threadIdx.x;
    out[idx] = fmaf(a0, out[idx], a1 * k2d[idx]);
}

extern "C" void kernel_launch(void* const* d_in, const int* in_sizes, int n_in,
                              void* d_out, int out_size, void* d_ws, size_t ws_size,
                              hipStream_t stream)
{
    const float* x      = (const float*)d_in[0];
    const float* w_key  = (const float*)d_in[1];
    const float* bnk_g  = (const float*)d_in[2];
    const float* bnk_b  = (const float*)d_in[3];
    const float* bnk_m  = (const float*)d_in[4];
    const float* bnk_v  = (const float*)d_in[5];
    const float* w_e1   = (const float*)d_in[6];
    const float* bne_g  = (const float*)d_in[7];
    const float* bne_b  = (const float*)d_in[8];
    const float* bne_m  = (const float*)d_in[9];
    const float* bne_v  = (const float*)d_in[10];
    const float* w_e2   = (const float*)d_in[11];
    const float* b_e2   = (const float*)d_in[12];
    const float* gn_g   = (const float*)d_in[13];
    const float* gn_b   = (const float*)d_in[14];
    const float* w_1x1  = (const float*)d_in[15];
    const float* bn1_g  = (const float*)d_in[16];
    const float* bn1_b  = (const float*)d_in[17];
    const float* bn1_m  = (const float*)d_in[18];
    const float* bn1_v  = (const float*)d_in[19];
    const float* bn2_g  = (const float*)d_in[20];
    const float* bn2_b  = (const float*)d_in[21];
    const float* bn2_m  = (const float*)d_in[22];
    const float* bn2_v  = (const float*)d_in[23];
    const float* w_se1  = (const float*)d_in[24];
    const float* b_se1  = (const float*)d_in[25];
    const float* bnse_g = (const float*)d_in[26];
    const float* bnse_b = (const float*)d_in[27];
    const float* bnse_m = (const float*)d_in[28];
    const float* bnse_v = (const float*)d_in[29];
    const float* w_se2  = (const float*)d_in[30];
    const float* b_se2  = (const float*)d_in[31];

    float* ws    = (float*)d_ws;
    float* k2d   = ws;
    float* v     = ws + 16777216;
    float* wd    = ws + 33554432;
    float* st    = ws + 46137344;
    float* gnsum  = st;
    float* gnsq   = st + 1024;
    float* gap    = st + 2048;
    float* gnmean = st + 2560;
    float* gnrstd = st + 3584;
    float* attn   = st + 4608;

    hipMemsetAsync(gnsum, 0, 2560 * sizeof(float), stream);

    kA_key<<<32 * 4 * 16, 256, 0, stream>>>(x, w_key, bnk_g, bnk_b, bnk_m, bnk_v, k2d, gap);
    kB_val<<<32 * 16 * 4, 256, 0, stream>>>(x, w_1x1, bn1_g, bn1_b, bn1_m, bn1_v, v);
    kC_wd<<<32 * 16, 256, 0, stream>>>(x, k2d, w_e1, bne_g, bne_b, bne_m, bne_v,
                                       w_e2, b_e2, wd, gnsum, gnsq);
    kC2_gn<<<4, 256, 0, stream>>>(gnsum, gnsq, gnmean, gnrstd);
    kD_agg<<<32 * 128 * 16, 256, 0, stream>>>(wd, v, gnmean, gnrstd, gn_g, gn_b,
                                              bn2_g, bn2_b, bn2_m, bn2_v,
                                              (float*)d_out, gap);
    kE_attn<<<1, 256, 0, stream>>>(gap, w_se1, b_se1, bnse_g, bnse_b, bnse_m, bnse_v,
                                   w_se2, b_se2, attn);
    kF_out<<<32 * 128 * 16, 256, 0, stream>>>((float*)d_out, k2d, attn);
}

// Round 3
// 592.134 us; speedup vs baseline: 1.3754x; 1.1640x over previous
//
#include <hip/hip_runtime.h>

#define EPSV 1e-5f

// Problem constants: B=4 clips, N=8 frames, B2=32, C=128, H=W=64, HW=4096, KS=3
// Workspace layout (floats):
//   k2d  @ 0         : 16777216
//   v    @ 16777216  : 16777216
//   wd   @ 33554432  : 12582912
//   stats@ 46137344  : gnsum[1024] gnsq[1024] gap[512] gnmean[1024] gnrstd[1024] attn[1024]
//   a_buf aliases gnsum (dead after kC2)

__device__ __forceinline__ void block_sum_atomic(float val, float* dst) {
    __shared__ float sm[4];
    #pragma unroll
    for (int off = 32; off; off >>= 1) val += __shfl_down(val, off, 64);
    int lane = threadIdx.x & 63, wid = threadIdx.x >> 6;
    if (lane == 0) sm[wid] = val;
    __syncthreads();
    if (threadIdx.x == 0) atomicAdd(dst, sm[0] + sm[1] + sm[2] + sm[3]);
}

// ---- kA: key_embed = ReLU(BN(grouped temporal conv3d)) + gap partial ----
__global__ __launch_bounds__(256) void kA_key(
    const float* __restrict__ x, const float* __restrict__ wk,
    const float* __restrict__ g, const float* __restrict__ bb,
    const float* __restrict__ m, const float* __restrict__ vr,
    float* __restrict__ k2d, float* __restrict__ gap)
{
    int tile = blockIdx.x & 15;
    int grp  = (blockIdx.x >> 4) & 3;
    int b2   = blockIdx.x >> 6;
    int hw   = tile * 256 + threadIdx.x;
    int bi = b2 >> 3, ni = b2 & 7;
    int gch = grp * 32;
    float acc[32];
    #pragma unroll
    for (int i = 0; i < 32; ++i) acc[i] = 0.f;
    #pragma unroll
    for (int dk = 0; dk < 3; ++dk) {
        int nf = ni + dk - 1;
        if (nf >= 0 && nf < 8) {
            const float* xp = x + ((bi * 8 + nf) * 128 + gch) * 4096 + hw;
            const float* wp = wk + gch * 96 + dk;
            for (int ci = 0; ci < 32; ++ci) {
                float xv = xp[ci * 4096];
                #pragma unroll
                for (int o8 = 0; o8 < 32; ++o8)
                    acc[o8] = fmaf(xv, wp[o8 * 96 + ci * 3], acc[o8]);
            }
        }
    }
    __shared__ float ssum[32][4];
    int lane = threadIdx.x & 63, wid = threadIdx.x >> 6;
    #pragma unroll
    for (int o8 = 0; o8 < 32; ++o8) {
        int o = gch + o8;
        float s = g[o] * rsqrtf(vr[o] + EPSV);
        float val = fmaxf(fmaf(acc[o8], s, bb[o] - m[o] * s), 0.f);
        k2d[(b2 * 128 + o) * 4096 + hw] = val;
        #pragma unroll
        for (int off = 32; off; off >>= 1) val += __shfl_down(val, off, 64);
        if (lane == 0) ssum[o8][wid] = val;
    }
    __syncthreads();
    if (threadIdx.x < 32) {
        float* sr = ssum[threadIdx.x];
        atomicAdd(&gap[bi * 128 + gch + threadIdx.x], sr[0] + sr[1] + sr[2] + sr[3]);
    }
}

// ---- kB: v = BN(x @ w_1x1), float4 scalar weight loads ----
__global__ __launch_bounds__(256) void kB_val(
    const float* __restrict__ x, const float* __restrict__ w,
    const float* __restrict__ g, const float* __restrict__ bb,
    const float* __restrict__ m, const float* __restrict__ vr,
    float* __restrict__ vout)
{
    int oc   = blockIdx.x & 3;
    int tile = (blockIdx.x >> 2) & 15;
    int b2   = blockIdx.x >> 6;
    int hw   = tile * 256 + threadIdx.x;
    const float* xp = x + b2 * 128 * 4096 + hw;
    const float* wp = w + oc * 32 * 128;
    float acc[32];
    #pragma unroll
    for (int i = 0; i < 32; ++i) acc[i] = 0.f;
    for (int c = 0; c < 128; c += 4) {
        float q0 = xp[(c + 0) * 4096];
        float q1 = xp[(c + 1) * 4096];
        float q2 = xp[(c + 2) * 4096];
        float q3 = xp[(c + 3) * 4096];
        #pragma unroll
        for (int o8 = 0; o8 < 32; ++o8) {
            const float4 w4 = *(const float4*)(wp + o8 * 128 + c);
            acc[o8] = fmaf(q0, w4.x, acc[o8]);
            acc[o8] = fmaf(q1, w4.y, acc[o8]);
            acc[o8] = fmaf(q2, w4.z, acc[o8]);
            acc[o8] = fmaf(q3, w4.w, acc[o8]);
        }
    }
    #pragma unroll
    for (int o8 = 0; o8 < 32; ++o8) {
        int o = oc * 32 + o8;
        float s = g[o] * rsqrtf(vr[o] + EPSV);
        vout[(b2 * 128 + o) * 4096 + hw] = fmaf(acc[o8], s, bb[o] - m[o] * s);
    }
}

// ---- kC: e = ReLU(BN([x;k2d]@w_e1)), wd = e@w_e2+b, GN partials ----
// Block = 64 pixels x 4 wave-quarters. Wave q: e-channels q*16..+15, wd rows q*24..+23.
__global__ __launch_bounds__(256, 8) void kC_wd(
    const float* __restrict__ x, const float* __restrict__ k2d,
    const float* __restrict__ we1,
    const float* __restrict__ eg, const float* __restrict__ eb,
    const float* __restrict__ em, const float* __restrict__ ev,
    const float* __restrict__ we2, const float* __restrict__ be2,
    float* __restrict__ wd, float* __restrict__ gnsum, float* __restrict__ gnsq)
{
    int tid  = threadIdx.x;
    int px   = tid & 63;
    int q    = __builtin_amdgcn_readfirstlane(tid >> 6);   // wave-uniform
    int tile = blockIdx.x & 63;
    int b2   = blockIdx.x >> 6;
    int hw   = tile * 64 + px;

    const float* xp  = x   + b2 * 128 * 4096 + hw;
    const float* kp  = k2d + b2 * 128 * 4096 + hw;
    const float* w1q = we1 + q * 16 * 256;

    float acc[16];
    #pragma unroll
    for (int j = 0; j < 16; ++j) acc[j] = 0.f;

    for (int c = 0; c < 128; c += 4) {
        float q0 = xp[(c + 0) * 4096];
        float q1 = xp[(c + 1) * 4096];
        float q2 = xp[(c + 2) * 4096];
        float q3 = xp[(c + 3) * 4096];
        #pragma unroll
        for (int j = 0; j < 16; ++j) {
            const float4 w4 = *(const float4*)(w1q + j * 256 + c);
            acc[j] = fmaf(q0, w4.x, acc[j]);
            acc[j] = fmaf(q1, w4.y, acc[j]);
            acc[j] = fmaf(q2, w4.z, acc[j]);
            acc[j] = fmaf(q3, w4.w, acc[j]);
        }
    }
    for (int c = 0; c < 128; c += 4) {
        float q0 = kp[(c + 0) * 4096];
        float q1 = kp[(c + 1) * 4096];
        float q2 = kp[(c + 2) * 4096];
        float q3 = kp[(c + 3) * 4096];
        #pragma unroll
        for (int j = 0; j < 16; ++j) {
            const float4 w4 = *(const float4*)(w1q + j * 256 + 128 + c);
            acc[j] = fmaf(q0, w4.x, acc[j]);
            acc[j] = fmaf(q1, w4.y, acc[j]);
            acc[j] = fmaf(q2, w4.z, acc[j]);
            acc[j] = fmaf(q3, w4.w, acc[j]);
        }
    }

    __shared__ float e_s[64][68];   // stride 68: 16B-aligned rows, rotated banks
    #pragma unroll
    for (int j = 0; j < 16; ++j) {
        int eo = q * 16 + j;
        float s = eg[eo] * rsqrtf(ev[eo] + EPSV);
        e_s[px][eo] = fmaxf(fmaf(acc[j], s, eb[eo] - em[eo] * s), 0.f);
    }
    __syncthreads();

    float wa[24];
    const float* w2q = we2 + q * 24 * 64;
    #pragma unroll
    for (int j = 0; j < 24; ++j) wa[j] = be2[q * 24 + j];
    for (int c = 0; c < 64; c += 4) {
        const float4 e4 = *(const float4*)&e_s[px][c];
        #pragma unroll
        for (int j = 0; j < 24; ++j) {
            const float4 w4 = *(const float4*)(w2q + j * 64 + c);
            wa[j] = fmaf(e4.x, w4.x, wa[j]);
            wa[j] = fmaf(e4.y, w4.y, wa[j]);
            wa[j] = fmaf(e4.z, w4.z, wa[j]);
            wa[j] = fmaf(e4.w, w4.w, wa[j]);
        }
    }

    float* wdp = wd + (b2 * 96 + q * 24) * 4096 + hw;
    #pragma unroll
    for (int jj = 0; jj < 8; ++jj) {       // c1 group = q*8 + jj
        float lsum = 0.f, lsq = 0.f;
        #pragma unroll
        for (int k = 0; k < 3; ++k) {
            float vwa = wa[jj * 3 + k];
            wdp[(jj * 3 + k) * 4096] = vwa;
            lsum += vwa; lsq += vwa * vwa;
        }
        #pragma unroll
        for (int off = 32; off; off >>= 1) {
            lsum += __shfl_down(lsum, off, 64);
            lsq  += __shfl_down(lsq,  off, 64);
        }
        if (px == 0) {
            atomicAdd(&gnsum[b2 * 32 + q * 8 + jj], lsum);
            atomicAdd(&gnsq [b2 * 32 + q * 8 + jj], lsq);
        }
    }
}

// ---- kC2: finalize GroupNorm stats ----
__global__ __launch_bounds__(256) void kC2_gn(
    const float* __restrict__ gnsum, const float* __restrict__ gnsq,
    float* __restrict__ gnmean, float* __restrict__ gnrstd)
{
    int idx = blockIdx.x * 256 + threadIdx.x;
    const float inv = 1.f / 12288.f;
    float mu  = gnsum[idx] * inv;
    float var = fmaf(gnsq[idx], inv, -mu * mu);
    gnmean[idx] = mu;
    gnrstd[idx] = rsqrtf(fmaxf(var, 0.f) + EPSV);
}

// ---- kD: agg = SiLU(BN2(sum_k GN(wd) * unfold(v))) -> d_out, + gap partial ----
__global__ __launch_bounds__(256) void kD_agg(
    const float* __restrict__ wd, const float* __restrict__ v,
    const float* __restrict__ gnmean, const float* __restrict__ gnrstd,
    const float* __restrict__ gng, const float* __restrict__ gnb,
    const float* __restrict__ g, const float* __restrict__ bb,
    const float* __restrict__ m, const float* __restrict__ vr,
    float* __restrict__ out, float* __restrict__ gap)
{
    int tile = blockIdx.x & 15;
    int c    = (blockIdx.x >> 4) & 127;
    int b2   = blockIdx.x >> 11;
    int hw   = tile * 256 + threadIdx.x;
    int bi = b2 >> 3, ni = b2 & 7;
    int c1 = c >> 2;
    float mu = gnmean[b2 * 32 + c1], rs = gnrstd[b2 * 32 + c1];
    float acc = 0.f;
    #pragma unroll
    for (int k = 0; k < 3; ++k) {
        int nf = ni + k - 1;
        if (nf >= 0 && nf < 8) {
            int wo = c1 * 3 + k;
            float wv = wd[(b2 * 96 + wo) * 4096 + hw];
            float wn = fmaf((wv - mu) * rs, gng[wo], gnb[wo]);
            float vvv = v[((bi * 8 + nf) * 128 + c) * 4096 + hw];
            acc = fmaf(wn, vvv, acc);
        }
    }
    float s = g[c] * rsqrtf(vr[c] + EPSV);
    float y = fmaf(acc, s, bb[c] - m[c] * s);
    float fy = y / (1.f + __expf(-y));
    out[(b2 * 128 + c) * 4096 + hw] = fy;
    block_sum_atomic(fy, &gap[bi * 128 + c]);
}

// ---- kE1: a = ReLU(BNvec(gap/32768 @ w1^T + b1)) ----
__global__ __launch_bounds__(256) void kE1_a(
    const float* __restrict__ gap,
    const float* __restrict__ w1, const float* __restrict__ b1,
    const float* __restrict__ g, const float* __restrict__ bb,
    const float* __restrict__ m, const float* __restrict__ vr,
    float* __restrict__ a_buf)
{
    int idx = blockIdx.x * 256 + threadIdx.x;   // grid 2 -> 512
    int bi = idx >> 7, oc = idx & 127;
    float acc = b1[oc];
    const float* gp = gap + bi * 128;
    const float* wp = w1 + oc * 128;
    for (int c = 0; c < 128; c += 4) {
        const float4 w4 = *(const float4*)(wp + c);
        acc = fmaf(gp[c + 0] * (1.f / 32768.f), w4.x, acc);
        acc = fmaf(gp[c + 1] * (1.f / 32768.f), w4.y, acc);
        acc = fmaf(gp[c + 2] * (1.f / 32768.f), w4.z, acc);
        acc = fmaf(gp[c + 3] * (1.f / 32768.f), w4.w, acc);
    }
    float s = g[oc] * rsqrtf(vr[oc] + EPSV);
    a_buf[bi * 128 + oc] = fmaxf(fmaf(acc, s, bb[oc] - m[oc] * s), 0.f);
}

// ---- kE2: attn = softmax over radix-2 pairs of a @ w2^T + b2 ----
__global__ __launch_bounds__(256) void kE2_attn(
    const float* __restrict__ a_buf,
    const float* __restrict__ w2, const float* __restrict__ b2v,
    float* __restrict__ attn)
{
    int idx = blockIdx.x * 256 + threadIdx.x;   // grid 2 -> 512
    int bi = idx >> 7, cc = idx & 127;
    float l0 = b2v[cc * 2], l1 = b2v[cc * 2 + 1];
    const float* ap  = a_buf + bi * 128;
    const float* w0p = w2 + (cc * 2) * 128;
    const float* w1p = w2 + (cc * 2 + 1) * 128;
    for (int j = 0; j < 128; j += 4) {
        const float4 wa4 = *(const float4*)(w0p + j);
        const float4 wb4 = *(const float4*)(w1p + j);
        l0 = fmaf(ap[j + 0], wa4.x, l0); l1 = fmaf(ap[j + 0], wb4.x, l1);
        l0 = fmaf(ap[j + 1], wa4.y, l0); l1 = fmaf(ap[j + 1], wb4.y, l1);
        l0 = fmaf(ap[j + 2], wa4.z, l0); l1 = fmaf(ap[j + 2], wb4.z, l1);
        l0 = fmaf(ap[j + 3], wa4.w, l0); l1 = fmaf(ap[j + 3], wb4.w, l1);
    }
    float mx = fmaxf(l0, l1);
    float e0 = __expf(l0 - mx), e1 = __expf(l1 - mx);
    float inv = 1.f / (e0 + e1);
    attn[bi * 256 + cc * 2]     = e0 * inv;
    attn[bi * 256 + cc * 2 + 1] = e1 * inv;
}

// ---- kF: out = attn0*agg + attn1*k2d ----
__global__ __launch_bounds__(256) void kF_out(
    float* __restrict__ out, const float* __restrict__ k2d,
    const float* __restrict__ attn)
{
    int tile = blockIdx.x & 15;
    int c    = (blockIdx.x >> 4) & 127;
    int b2   = blockIdx.x >> 11;
    int bi   = b2 >> 3;
    float a0 = attn[bi * 256 + c * 2];
    float a1 = attn[bi * 256 + c * 2 + 1];
    int idx = (b2 * 128 + c) * 4096 + tile * 256 + threadIdx.x;
    out[idx] = fmaf(a0, out[idx], a1 * k2d[idx]);
}

extern "C" void kernel_launch(void* const* d_in, const int* in_sizes, int n_in,
                              void* d_out, int out_size, void* d_ws, size_t ws_size,
                              hipStream_t stream)
{
    const float* x      = (const float*)d_in[0];
    const float* w_key  = (const float*)d_in[1];
    const float* bnk_g  = (const float*)d_in[2];
    const float* bnk_b  = (const float*)d_in[3];
    const float* bnk_m  = (const float*)d_in[4];
    const float* bnk_v  = (const float*)d_in[5];
    const float* w_e1   = (const float*)d_in[6];
    const float* bne_g  = (const float*)d_in[7];
    const float* bne_b  = (const float*)d_in[8];
    const float* bne_m  = (const float*)d_in[9];
    const float* bne_v  = (const float*)d_in[10];
    const float* w_e2   = (const float*)d_in[11];
    const float* b_e2   = (const float*)d_in[12];
    const float* gn_g   = (const float*)d_in[13];
    const float* gn_b   = (const float*)d_in[14];
    const float* w_1x1  = (const float*)d_in[15];
    const float* bn1_g  = (const float*)d_in[16];
    const float* bn1_b  = (const float*)d_in[17];
    const float* bn1_m  = (const float*)d_in[18];
    const float* bn1_v  = (const float*)d_in[19];
    const float* bn2_g  = (const float*)d_in[20];
    const float* bn2_b  = (const float*)d_in[21];
    const float* bn2_m  = (const float*)d_in[22];
    const float* bn2_v  = (const float*)d_in[23];
    const float* w_se1  = (const float*)d_in[24];
    const float* b_se1  = (const float*)d_in[25];
    const float* bnse_g = (const float*)d_in[26];
    const float* bnse_b = (const float*)d_in[27];
    const float* bnse_m = (const float*)d_in[28];
    const float* bnse_v = (const float*)d_in[29];
    const float* w_se2  = (const float*)d_in[30];
    const float* b_se2  = (const float*)d_in[31];

    float* ws    = (float*)d_ws;
    float* k2d   = ws;
    float* v     = ws + 16777216;
    float* wd    = ws + 33554432;
    float* st    = ws + 46137344;
    float* gnsum  = st;
    float* gnsq   = st + 1024;
    float* gap    = st + 2048;
    float* gnmean = st + 2560;
    float* gnrstd = st + 3584;
    float* attn   = st + 4608;
    float* a_buf  = st;            // aliases gnsum (dead after kC2)

    hipMemsetAsync(gnsum, 0, 2560 * sizeof(float), stream);

    kA_key<<<32 * 4 * 16, 256, 0, stream>>>(x, w_key, bnk_g, bnk_b, bnk_m, bnk_v, k2d, gap);
    kB_val<<<32 * 16 * 4, 256, 0, stream>>>(x, w_1x1, bn1_g, bn1_b, bn1_m, bn1_v, v);
    kC_wd<<<32 * 64, 256, 0, stream>>>(x, k2d, w_e1, bne_g, bne_b, bne_m, bne_v,
                                       w_e2, b_e2, wd, gnsum, gnsq);
    kC2_gn<<<4, 256, 0, stream>>>(gnsum, gnsq, gnmean, gnrstd);
    kD_agg<<<32 * 128 * 16, 256, 0, stream>>>(wd, v, gnmean, gnrstd, gn_g, gn_b,
                                              bn2_g, bn2_b, bn2_m, bn2_v,
                                              (float*)d_out, gap);
    kE1_a<<<2, 256, 0, stream>>>(gap, w_se1, b_se1, bnse_g, bnse_b, bnse_m, bnse_v, a_buf);
    kE2_attn<<<2, 256, 0, stream>>>(a_buf, w_se2, b_se2, attn);
    kF_out<<<32 * 128 * 16, 256, 0, stream>>>((float*)d_out, k2d, attn);
}

// Round 4
// 368.339 us; speedup vs baseline: 2.2110x; 1.6076x over previous
//
#include <hip/hip_runtime.h>

#define EPSV 1e-5f

// Problem constants: B=4, N=8, B2=32, C=128, H=W=64, HW=4096, KS=3
// Workspace (floats): k2d@0 (16777216), v@16777216 (16777216), wd@33554432 (12582912),
// stats@46137344: gnsum[1024] gnsq[1024] gap[512] gnmean[1024] gnrstd[1024] attn[1024]

__device__ __forceinline__ void block_sum_atomic(float val, float* dst) {
    __shared__ float sm[4];
    #pragma unroll
    for (int off = 32; off; off >>= 1) val += __shfl_down(val, off, 64);
    int lane = threadIdx.x & 63, wid = threadIdx.x >> 6;
    if (lane == 0) sm[wid] = val;
    __syncthreads();
    if (threadIdx.x == 0) atomicAdd(dst, sm[0] + sm[1] + sm[2] + sm[3]);
}

// ---- kA: key_embed = ReLU(BN(grouped temporal conv3d)) + gap partial ----
// Block: 16 output channels (half group) x 1024-px strip; thread = 4 px (float4).
__global__ __launch_bounds__(256, 4) void kA_key(
    const float* __restrict__ x, const float* __restrict__ wk,
    const float* __restrict__ g, const float* __restrict__ bb,
    const float* __restrict__ m, const float* __restrict__ vr,
    float* __restrict__ k2d, float* __restrict__ gap)
{
    int blk   = blockIdx.x;
    int strip = blk & 3;
    int half  = (blk >> 2) & 1;
    int grp   = (blk >> 3) & 3;
    int b2    = blk >> 5;
    int px0   = strip * 1024 + threadIdx.x * 4;
    int bi = b2 >> 3, ni = b2 & 7;
    int gch = grp * 32;
    int ob  = gch + half * 16;

    float acc[16][4];
    #pragma unroll
    for (int j = 0; j < 16; ++j)
        acc[j][0] = acc[j][1] = acc[j][2] = acc[j][3] = 0.f;

    #pragma unroll
    for (int dk = 0; dk < 3; ++dk) {
        int nf = ni + dk - 1;
        if (nf >= 0 && nf < 8) {
            const float* xp  = x + ((bi * 8 + nf) * 128 + gch) * 4096 + px0;
            const float* wkp = wk + ob * 96 + dk;
            #pragma unroll 4
            for (int ci = 0; ci < 32; ++ci) {
                const float4 xv = *(const float4*)(xp + ci * 4096);
                #pragma unroll
                for (int j = 0; j < 16; ++j) {
                    float wv = wkp[j * 96 + ci * 3];
                    acc[j][0] = fmaf(xv.x, wv, acc[j][0]);
                    acc[j][1] = fmaf(xv.y, wv, acc[j][1]);
                    acc[j][2] = fmaf(xv.z, wv, acc[j][2]);
                    acc[j][3] = fmaf(xv.w, wv, acc[j][3]);
                }
            }
        }
    }

    int lane = threadIdx.x & 63, wid = threadIdx.x >> 6;
    __shared__ float ssum[16][4];
    #pragma unroll
    for (int j = 0; j < 16; ++j) {
        int o = ob + j;
        float s = g[o] * rsqrtf(vr[o] + EPSV);
        float t = bb[o] - m[o] * s;
        float4 r;
        r.x = fmaxf(fmaf(acc[j][0], s, t), 0.f);
        r.y = fmaxf(fmaf(acc[j][1], s, t), 0.f);
        r.z = fmaxf(fmaf(acc[j][2], s, t), 0.f);
        r.w = fmaxf(fmaf(acc[j][3], s, t), 0.f);
        *(float4*)(k2d + (b2 * 128 + o) * 4096 + px0) = r;
        float lsum = r.x + r.y + r.z + r.w;
        #pragma unroll
        for (int off = 32; off; off >>= 1) lsum += __shfl_down(lsum, off, 64);
        if (lane == 0) ssum[j][wid] = lsum;
    }
    __syncthreads();
    if (threadIdx.x < 16) {
        float* sr = ssum[threadIdx.x];
        atomicAdd(&gap[bi * 128 + ob + threadIdx.x], sr[0] + sr[1] + sr[2] + sr[3]);
    }
}

// ---- kB: v = BN(x @ w_1x1); 16 oc x 1024-px strip; thread = 4 px ----
__global__ __launch_bounds__(256, 4) void kB_val(
    const float* __restrict__ x, const float* __restrict__ w,
    const float* __restrict__ g, const float* __restrict__ bb,
    const float* __restrict__ m, const float* __restrict__ vr,
    float* __restrict__ vout)
{
    int blk   = blockIdx.x;
    int ocg   = blk & 7;
    int strip = (blk >> 3) & 3;
    int b2    = blk >> 5;
    int px0   = strip * 1024 + threadIdx.x * 4;
    const float* xp = x + b2 * 128 * 4096 + px0;
    const float* wp = w + ocg * 16 * 128;

    float acc[16][4];
    #pragma unroll
    for (int j = 0; j < 16; ++j)
        acc[j][0] = acc[j][1] = acc[j][2] = acc[j][3] = 0.f;

    #pragma unroll 4
    for (int c = 0; c < 128; ++c) {
        const float4 xv = *(const float4*)(xp + c * 4096);
        #pragma unroll
        for (int j = 0; j < 16; ++j) {
            float wv = wp[j * 128 + c];
            acc[j][0] = fmaf(xv.x, wv, acc[j][0]);
            acc[j][1] = fmaf(xv.y, wv, acc[j][1]);
            acc[j][2] = fmaf(xv.z, wv, acc[j][2]);
            acc[j][3] = fmaf(xv.w, wv, acc[j][3]);
        }
    }
    #pragma unroll
    for (int j = 0; j < 16; ++j) {
        int o = ocg * 16 + j;
        float s = g[o] * rsqrtf(vr[o] + EPSV);
        float t = bb[o] - m[o] * s;
        float4 r;
        r.x = fmaf(acc[j][0], s, t);
        r.y = fmaf(acc[j][1], s, t);
        r.z = fmaf(acc[j][2], s, t);
        r.w = fmaf(acc[j][3], s, t);
        *(float4*)(vout + (b2 * 128 + o) * 4096 + px0) = r;
    }
}

// ---- kC: e = ReLU(BN([x;k2d]@w_e1)), wd = e@w_e2+b, GN partials ----
// Block = 256 px; wave q computes e-channels [16q,16q+16) then wd rows [24q,24q+24).
// Thread = 4 px (float4). e exchanged via LDS [64ch][256px] (row-uniform access).
__global__ __launch_bounds__(256, 2) void kC_wd(
    const float* __restrict__ x, const float* __restrict__ k2d,
    const float* __restrict__ we1,
    const float* __restrict__ eg, const float* __restrict__ eb,
    const float* __restrict__ em, const float* __restrict__ ev,
    const float* __restrict__ we2, const float* __restrict__ be2,
    float* __restrict__ wd, float* __restrict__ gnsum, float* __restrict__ gnsq)
{
    int tid  = threadIdx.x;
    int lane = tid & 63;
    int q    = __builtin_amdgcn_readfirstlane(tid >> 6);
    int tile = blockIdx.x & 15;
    int b2   = blockIdx.x >> 4;
    int pxl  = lane * 4;
    int px0  = tile * 256 + pxl;

    const float* xp  = x   + b2 * 128 * 4096 + px0;
    const float* kp  = k2d + b2 * 128 * 4096 + px0;
    const float* w1q = we1 + q * 16 * 256;

    float acc[16][4];
    #pragma unroll
    for (int j = 0; j < 16; ++j)
        acc[j][0] = acc[j][1] = acc[j][2] = acc[j][3] = 0.f;

    #pragma unroll 4
    for (int c = 0; c < 128; ++c) {
        const float4 xv = *(const float4*)(xp + c * 4096);
        #pragma unroll
        for (int j = 0; j < 16; ++j) {
            float wv = w1q[j * 256 + c];
            acc[j][0] = fmaf(xv.x, wv, acc[j][0]);
            acc[j][1] = fmaf(xv.y, wv, acc[j][1]);
            acc[j][2] = fmaf(xv.z, wv, acc[j][2]);
            acc[j][3] = fmaf(xv.w, wv, acc[j][3]);
        }
    }
    #pragma unroll 4
    for (int c = 0; c < 128; ++c) {
        const float4 xv = *(const float4*)(kp + c * 4096);
        #pragma unroll
        for (int j = 0; j < 16; ++j) {
            float wv = w1q[j * 256 + 128 + c];
            acc[j][0] = fmaf(xv.x, wv, acc[j][0]);
            acc[j][1] = fmaf(xv.y, wv, acc[j][1]);
            acc[j][2] = fmaf(xv.z, wv, acc[j][2]);
            acc[j][3] = fmaf(xv.w, wv, acc[j][3]);
        }
    }

    __shared__ float e_s[64][256];   // 64 KB; row index uniform per access -> conflict-free
    #pragma unroll
    for (int j = 0; j < 16; ++j) {
        int eo = q * 16 + j;
        float s = eg[eo] * rsqrtf(ev[eo] + EPSV);
        float t = eb[eo] - em[eo] * s;
        float4 r;
        r.x = fmaxf(fmaf(acc[j][0], s, t), 0.f);
        r.y = fmaxf(fmaf(acc[j][1], s, t), 0.f);
        r.z = fmaxf(fmaf(acc[j][2], s, t), 0.f);
        r.w = fmaxf(fmaf(acc[j][3], s, t), 0.f);
        *(float4*)&e_s[eo][pxl] = r;
    }
    __syncthreads();

    float wa[24][4];
    #pragma unroll
    for (int j = 0; j < 24; ++j) {
        float b = be2[q * 24 + j];
        wa[j][0] = wa[j][1] = wa[j][2] = wa[j][3] = b;
    }
    const float* w2q = we2 + q * 24 * 64;
    #pragma unroll 4
    for (int c = 0; c < 64; ++c) {
        const float4 ev4 = *(const float4*)&e_s[c][pxl];
        #pragma unroll
        for (int j = 0; j < 24; ++j) {
            float wv = w2q[j * 64 + c];
            wa[j][0] = fmaf(ev4.x, wv, wa[j][0]);
            wa[j][1] = fmaf(ev4.y, wv, wa[j][1]);
            wa[j][2] = fmaf(ev4.z, wv, wa[j][2]);
            wa[j][3] = fmaf(ev4.w, wv, wa[j][3]);
        }
    }

    float* wdp = wd + (b2 * 96 + q * 24) * 4096 + px0;
    #pragma unroll
    for (int j = 0; j < 24; ++j) {
        float4 r; r.x = wa[j][0]; r.y = wa[j][1]; r.z = wa[j][2]; r.w = wa[j][3];
        *(float4*)(wdp + j * 4096) = r;
    }

    #pragma unroll
    for (int jj = 0; jj < 8; ++jj) {
        float lsum = 0.f, lsq = 0.f;
        #pragma unroll
        for (int k = 0; k < 3; ++k)
            #pragma unroll
            for (int p = 0; p < 4; ++p) {
                float vv = wa[jj * 3 + k][p];
                lsum += vv; lsq += vv * vv;
            }
        #pragma unroll
        for (int off = 32; off; off >>= 1) {
            lsum += __shfl_down(lsum, off, 64);
            lsq  += __shfl_down(lsq,  off, 64);
        }
        if (lane == 0) {
            atomicAdd(&gnsum[b2 * 32 + q * 8 + jj], lsum);
            atomicAdd(&gnsq [b2 * 32 + q * 8 + jj], lsq);
        }
    }
}

// ---- kC2: finalize GroupNorm stats ----
__global__ __launch_bounds__(256) void kC2_gn(
    const float* __restrict__ gnsum, const float* __restrict__ gnsq,
    float* __restrict__ gnmean, float* __restrict__ gnrstd)
{
    int idx = blockIdx.x * 256 + threadIdx.x;
    const float inv = 1.f / 12288.f;
    float mu  = gnsum[idx] * inv;
    float var = fmaf(gnsq[idx], inv, -mu * mu);
    gnmean[idx] = mu;
    gnrstd[idx] = rsqrtf(fmaxf(var, 0.f) + EPSV);
}

// ---- kD: agg = SiLU(BN2(sum_k GN(wd)*unfold(v))) -> d_out, + gap; thread = 4 px ----
__global__ __launch_bounds__(256, 8) void kD_agg(
    const float* __restrict__ wd, const float* __restrict__ v,
    const float* __restrict__ gnmean, const float* __restrict__ gnrstd,
    const float* __restrict__ gng, const float* __restrict__ gnb,
    const float* __restrict__ g, const float* __restrict__ bb,
    const float* __restrict__ m, const float* __restrict__ vr,
    float* __restrict__ out, float* __restrict__ gap)
{
    int blk   = blockIdx.x;
    int strip = blk & 3;
    int c     = (blk >> 2) & 127;
    int b2    = blk >> 9;
    int px0   = strip * 1024 + threadIdx.x * 4;
    int bi = b2 >> 3, ni = b2 & 7;
    int c1 = c >> 2;
    float mu = gnmean[b2 * 32 + c1], rs = gnrstd[b2 * 32 + c1];

    float a0 = 0.f, a1 = 0.f, a2 = 0.f, a3 = 0.f;
    #pragma unroll
    for (int k = 0; k < 3; ++k) {
        int nf = ni + k - 1;
        if (nf >= 0 && nf < 8) {
            int wo = c1 * 3 + k;
            float gg = gng[wo], gb = gnb[wo];
            const float4 wv = *(const float4*)(wd + (b2 * 96 + wo) * 4096 + px0);
            const float4 vv = *(const float4*)(v + ((bi * 8 + nf) * 128 + c) * 4096 + px0);
            a0 = fmaf(fmaf((wv.x - mu) * rs, gg, gb), vv.x, a0);
            a1 = fmaf(fmaf((wv.y - mu) * rs, gg, gb), vv.y, a1);
            a2 = fmaf(fmaf((wv.z - mu) * rs, gg, gb), vv.z, a2);
            a3 = fmaf(fmaf((wv.w - mu) * rs, gg, gb), vv.w, a3);
        }
    }
    float s = g[c] * rsqrtf(vr[c] + EPSV);
    float t = bb[c] - m[c] * s;
    float4 r;
    float y;
    y = fmaf(a0, s, t); r.x = y / (1.f + __expf(-y));
    y = fmaf(a1, s, t); r.y = y / (1.f + __expf(-y));
    y = fmaf(a2, s, t); r.z = y / (1.f + __expf(-y));
    y = fmaf(a3, s, t); r.w = y / (1.f + __expf(-y));
    *(float4*)(out + (b2 * 128 + c) * 4096 + px0) = r;
    block_sum_atomic(r.x + r.y + r.z + r.w, &gap[bi * 128 + c]);
}

// ---- kE1: a = ReLU(BNvec(gap/32768 @ w1^T + b1)) ----
__global__ __launch_bounds__(256) void kE1_a(
    const float* __restrict__ gap,
    const float* __restrict__ w1, const float* __restrict__ b1,
    const float* __restrict__ g, const float* __restrict__ bb,
    const float* __restrict__ m, const float* __restrict__ vr,
    float* __restrict__ a_buf)
{
    int idx = blockIdx.x * 256 + threadIdx.x;
    int bi = idx >> 7, oc = idx & 127;
    float acc = b1[oc];
    const float* gp = gap + bi * 128;
    const float* wp = w1 + oc * 128;
    for (int c = 0; c < 128; c += 4) {
        const float4 w4 = *(const float4*)(wp + c);
        acc = fmaf(gp[c + 0] * (1.f / 32768.f), w4.x, acc);
        acc = fmaf(gp[c + 1] * (1.f / 32768.f), w4.y, acc);
        acc = fmaf(gp[c + 2] * (1.f / 32768.f), w4.z, acc);
        acc = fmaf(gp[c + 3] * (1.f / 32768.f), w4.w, acc);
    }
    float s = g[oc] * rsqrtf(vr[oc] + EPSV);
    a_buf[bi * 128 + oc] = fmaxf(fmaf(acc, s, bb[oc] - m[oc] * s), 0.f);
}

// ---- kE2: attn = softmax over radix-2 pairs ----
__global__ __launch_bounds__(256) void kE2_attn(
    const float* __restrict__ a_buf,
    const float* __restrict__ w2, const float* __restrict__ b2v,
    float* __restrict__ attn)
{
    int idx = blockIdx.x * 256 + threadIdx.x;
    int bi = idx >> 7, cc = idx & 127;
    float l0 = b2v[cc * 2], l1 = b2v[cc * 2 + 1];
    const float* ap  = a_buf + bi * 128;
    const float* w0p = w2 + (cc * 2) * 128;
    const float* w1p = w2 + (cc * 2 + 1) * 128;
    for (int j = 0; j < 128; j += 4) {
        const float4 wa4 = *(const float4*)(w0p + j);
        const float4 wb4 = *(const float4*)(w1p + j);
        l0 = fmaf(ap[j + 0], wa4.x, l0); l1 = fmaf(ap[j + 0], wb4.x, l1);
        l0 = fmaf(ap[j + 1], wa4.y, l0); l1 = fmaf(ap[j + 1], wb4.y, l1);
        l0 = fmaf(ap[j + 2], wa4.z, l0); l1 = fmaf(ap[j + 2], wb4.z, l1);
        l0 = fmaf(ap[j + 3], wa4.w, l0); l1 = fmaf(ap[j + 3], wb4.w, l1);
    }
    float mx = fmaxf(l0, l1);
    float e0 = __expf(l0 - mx), e1 = __expf(l1 - mx);
    float inv = 1.f / (e0 + e1);
    attn[bi * 256 + cc * 2]     = e0 * inv;
    attn[bi * 256 + cc * 2 + 1] = e1 * inv;
}

// ---- kF: out = attn0*agg + attn1*k2d; thread = 4 px ----
__global__ __launch_bounds__(256, 8) void kF_out(
    float* __restrict__ out, const float* __restrict__ k2d,
    const float* __restrict__ attn)
{
    int blk   = blockIdx.x;
    int strip = blk & 3;
    int c     = (blk >> 2) & 127;
    int b2    = blk >> 9;
    int bi    = b2 >> 3;
    float a0 = attn[bi * 256 + c * 2];
    float a1 = attn[bi * 256 + c * 2 + 1];
    int idx = (b2 * 128 + c) * 4096 + strip * 1024 + threadIdx.x * 4;
    float4 o4 = *(const float4*)(out + idx);
    float4 k4 = *(const float4*)(k2d + idx);
    float4 r;
    r.x = fmaf(a0, o4.x, a1 * k4.x);
    r.y = fmaf(a0, o4.y, a1 * k4.y);
    r.z = fmaf(a0, o4.z, a1 * k4.z);
    r.w = fmaf(a0, o4.w, a1 * k4.w);
    *(float4*)(out + idx) = r;
}

extern "C" void kernel_launch(void* const* d_in, const int* in_sizes, int n_in,
                              void* d_out, int out_size, void* d_ws, size_t ws_size,
                              hipStream_t stream)
{
    const float* x      = (const float*)d_in[0];
    const float* w_key  = (const float*)d_in[1];
    const float* bnk_g  = (const float*)d_in[2];
    const float* bnk_b  = (const float*)d_in[3];
    const float* bnk_m  = (const float*)d_in[4];
    const float* bnk_v  = (const float*)d_in[5];
    const float* w_e1   = (const float*)d_in[6];
    const float* bne_g  = (const float*)d_in[7];
    const float* bne_b  = (const float*)d_in[8];
    const float* bne_m  = (const float*)d_in[9];
    const float* bne_v  = (const float*)d_in[10];
    const float* w_e2   = (const float*)d_in[11];
    const float* b_e2   = (const float*)d_in[12];
    const float* gn_g   = (const float*)d_in[13];
    const float* gn_b   = (const float*)d_in[14];
    const float* w_1x1  = (const float*)d_in[15];
    const float* bn1_g  = (const float*)d_in[16];
    const float* bn1_b  = (const float*)d_in[17];
    const float* bn1_m  = (const float*)d_in[18];
    const float* bn1_v  = (const float*)d_in[19];
    const float* bn2_g  = (const float*)d_in[20];
    const float* bn2_b  = (const float*)d_in[21];
    const float* bn2_m  = (const float*)d_in[22];
    const float* bn2_v  = (const float*)d_in[23];
    const float* w_se1  = (const float*)d_in[24];
    const float* b_se1  = (const float*)d_in[25];
    const float* bnse_g = (const float*)d_in[26];
    const float* bnse_b = (const float*)d_in[27];
    const float* bnse_m = (const float*)d_in[28];
    const float* bnse_v = (const float*)d_in[29];
    const float* w_se2  = (const float*)d_in[30];
    const float* b_se2  = (const float*)d_in[31];

    float* ws    = (float*)d_ws;
    float* k2d   = ws;
    float* v     = ws + 16777216;
    float* wd    = ws + 33554432;
    float* st    = ws + 46137344;
    float* gnsum  = st;
    float* gnsq   = st + 1024;
    float* gap    = st + 2048;
    float* gnmean = st + 2560;
    float* gnrstd = st + 3584;
    float* attn   = st + 4608;
    float* a_buf  = st;            // aliases gnsum (dead after kC2)

    hipMemsetAsync(gnsum, 0, 2560 * sizeof(float), stream);

    kA_key<<<1024, 256, 0, stream>>>(x, w_key, bnk_g, bnk_b, bnk_m, bnk_v, k2d, gap);
    kB_val<<<1024, 256, 0, stream>>>(x, w_1x1, bn1_g, bn1_b, bn1_m, bn1_v, v);
    kC_wd<<<512, 256, 0, stream>>>(x, k2d, w_e1, bne_g, bne_b, bne_m, bne_v,
                                   w_e2, b_e2, wd, gnsum, gnsq);
    kC2_gn<<<4, 256, 0, stream>>>(gnsum, gnsq, gnmean, gnrstd);
    kD_agg<<<16384, 256, 0, stream>>>(wd, v, gnmean, gnrstd, gn_g, gn_b,
                                      bn2_g, bn2_b, bn2_m, bn2_v,
                                      (float*)d_out, gap);
    kE1_a<<<2, 256, 0, stream>>>(gap, w_se1, b_se1, bnse_g, bnse_b, bnse_m, bnse_v, a_buf);
    kE2_attn<<<2, 256, 0, stream>>>(a_buf, w_se2, b_se2, attn);
    kF_out<<<16384, 256, 0, stream>>>((float*)d_out, k2d, attn);
}

// Round 5
// 344.578 us; speedup vs baseline: 2.3635x; 1.0690x over previous
//
#include <hip/hip_runtime.h>

#define EPSV 1e-5f

// Problem constants: B=4, N=8, B2=32, C=128, H=W=64, HW=4096, KS=3
// Workspace (floats): k2d@0 (16777216), v@16777216 (16777216), wd@33554432 (12582912),
// stats@46137344: gnsum[1024] gnsq[1024] gap[512] gnmean[1024] gnrstd[1024] attn[1024]

__device__ __forceinline__ void block_sum_atomic(float val, float* dst) {
    __shared__ float sm[4];
    #pragma unroll
    for (int off = 32; off; off >>= 1) val += __shfl_down(val, off, 64);
    int lane = threadIdx.x & 63, wid = threadIdx.x >> 6;
    if (lane == 0) sm[wid] = val;
    __syncthreads();
    if (threadIdx.x == 0) atomicAdd(dst, sm[0] + sm[1] + sm[2] + sm[3]);
}

__device__ __forceinline__ unsigned bfbits(float f) {   // RNE f32->bf16 bits
    unsigned u = __float_as_uint(f);
    u += 0x7fff + ((u >> 16) & 1);
    return u >> 16;
}

// ---- kA: key_embed = ReLU(BN(grouped temporal conv3d)) + gap partial ----
// Block: 16 output channels (half group) x 1024-px strip; thread = 4 px (float4).
__global__ __launch_bounds__(256, 4) void kA_key(
    const float* __restrict__ x, const float* __restrict__ wk,
    const float* __restrict__ g, const float* __restrict__ bb,
    const float* __restrict__ m, const float* __restrict__ vr,
    float* __restrict__ k2d, float* __restrict__ gap)
{
    int blk   = blockIdx.x;
    int strip = blk & 3;
    int half  = (blk >> 2) & 1;
    int grp   = (blk >> 3) & 3;
    int b2    = blk >> 5;
    int px0   = strip * 1024 + threadIdx.x * 4;
    int bi = b2 >> 3, ni = b2 & 7;
    int gch = grp * 32;
    int ob  = gch + half * 16;

    float acc[16][4];
    #pragma unroll
    for (int j = 0; j < 16; ++j)
        acc[j][0] = acc[j][1] = acc[j][2] = acc[j][3] = 0.f;

    #pragma unroll
    for (int dk = 0; dk < 3; ++dk) {
        int nf = ni + dk - 1;
        if (nf >= 0 && nf < 8) {
            const float* xp  = x + ((bi * 8 + nf) * 128 + gch) * 4096 + px0;
            const float* wkp = wk + ob * 96 + dk;
            #pragma unroll 4
            for (int ci = 0; ci < 32; ++ci) {
                const float4 xv = *(const float4*)(xp + ci * 4096);
                #pragma unroll
                for (int j = 0; j < 16; ++j) {
                    float wv = wkp[j * 96 + ci * 3];
                    acc[j][0] = fmaf(xv.x, wv, acc[j][0]);
                    acc[j][1] = fmaf(xv.y, wv, acc[j][1]);
                    acc[j][2] = fmaf(xv.z, wv, acc[j][2]);
                    acc[j][3] = fmaf(xv.w, wv, acc[j][3]);
                }
            }
        }
    }

    int lane = threadIdx.x & 63, wid = threadIdx.x >> 6;
    __shared__ float ssum[16][4];
    #pragma unroll
    for (int j = 0; j < 16; ++j) {
        int o = ob + j;
        float s = g[o] * rsqrtf(vr[o] + EPSV);
        float t = bb[o] - m[o] * s;
        float4 r;
        r.x = fmaxf(fmaf(acc[j][0], s, t), 0.f);
        r.y = fmaxf(fmaf(acc[j][1], s, t), 0.f);
        r.z = fmaxf(fmaf(acc[j][2], s, t), 0.f);
        r.w = fmaxf(fmaf(acc[j][3], s, t), 0.f);
        *(float4*)(k2d + (b2 * 128 + o) * 4096 + px0) = r;
        float lsum = r.x + r.y + r.z + r.w;
        #pragma unroll
        for (int off = 32; off; off >>= 1) lsum += __shfl_down(lsum, off, 64);
        if (lane == 0) ssum[j][wid] = lsum;
    }
    __syncthreads();
    if (threadIdx.x < 16) {
        float* sr = ssum[threadIdx.x];
        atomicAdd(&gap[bi * 128 + ob + threadIdx.x], sr[0] + sr[1] + sr[2] + sr[3]);
    }
}

// ---- kB: v = BN(x @ w_1x1); 16 oc x 1024-px strip; thread = 4 px ----
__global__ __launch_bounds__(256, 4) void kB_val(
    const float* __restrict__ x, const float* __restrict__ w,
    const float* __restrict__ g, const float* __restrict__ bb,
    const float* __restrict__ m, const float* __restrict__ vr,
    float* __restrict__ vout)
{
    int blk   = blockIdx.x;
    int ocg   = blk & 7;
    int strip = (blk >> 3) & 3;
    int b2    = blk >> 5;
    int px0   = strip * 1024 + threadIdx.x * 4;
    const float* xp = x + b2 * 128 * 4096 + px0;
    const float* wp = w + ocg * 16 * 128;

    float acc[16][4];
    #pragma unroll
    for (int j = 0; j < 16; ++j)
        acc[j][0] = acc[j][1] = acc[j][2] = acc[j][3] = 0.f;

    #pragma unroll 4
    for (int c = 0; c < 128; ++c) {
        const float4 xv = *(const float4*)(xp + c * 4096);
        #pragma unroll
        for (int j = 0; j < 16; ++j) {
            float wv = wp[j * 128 + c];
            acc[j][0] = fmaf(xv.x, wv, acc[j][0]);
            acc[j][1] = fmaf(xv.y, wv, acc[j][1]);
            acc[j][2] = fmaf(xv.z, wv, acc[j][2]);
            acc[j][3] = fmaf(xv.w, wv, acc[j][3]);
        }
    }
    #pragma unroll
    for (int j = 0; j < 16; ++j) {
        int o = ocg * 16 + j;
        float s = g[o] * rsqrtf(vr[o] + EPSV);
        float t = bb[o] - m[o] * s;
        float4 r;
        r.x = fmaf(acc[j][0], s, t);
        r.y = fmaf(acc[j][1], s, t);
        r.z = fmaf(acc[j][2], s, t);
        r.w = fmaf(acc[j][3], s, t);
        *(float4*)(vout + (b2 * 128 + o) * 4096 + px0) = r;
    }
}

// ---- kC: e = ReLU(BN([x;k2d]@w_e1)), wd = e@w_e2+b, GN partials ----
// Block = 256 px; wave q computes e-channels [16q,16q+16) then wd rows [24q,24q+24).
// Thread = 4 px (float4). e exchanged via bf16 LDS [64ch][256px] = 32 KB -> 4 blocks/CU.
__global__ __launch_bounds__(256, 4) void kC_wd(
    const float* __restrict__ x, const float* __restrict__ k2d,
    const float* __restrict__ we1,
    const float* __restrict__ eg, const float* __restrict__ eb,
    const float* __restrict__ em, const float* __restrict__ ev,
    const float* __restrict__ we2, const float* __restrict__ be2,
    float* __restrict__ wd, float* __restrict__ gnsum, float* __restrict__ gnsq)
{
    int tid  = threadIdx.x;
    int lane = tid & 63;
    int q    = __builtin_amdgcn_readfirstlane(tid >> 6);
    int tile = blockIdx.x & 15;
    int b2   = blockIdx.x >> 4;
    int pxl  = lane * 4;
    int px0  = tile * 256 + pxl;

    const float* xp  = x   + b2 * 128 * 4096 + px0;
    const float* kp  = k2d + b2 * 128 * 4096 + px0;
    const float* w1q = we1 + q * 16 * 256;

    float acc[16][4];
    #pragma unroll
    for (int j = 0; j < 16; ++j)
        acc[j][0] = acc[j][1] = acc[j][2] = acc[j][3] = 0.f;

    #pragma unroll 4
    for (int c = 0; c < 128; ++c) {
        const float4 xv = *(const float4*)(xp + c * 4096);
        #pragma unroll
        for (int j = 0; j < 16; ++j) {
            float wv = w1q[j * 256 + c];
            acc[j][0] = fmaf(xv.x, wv, acc[j][0]);
            acc[j][1] = fmaf(xv.y, wv, acc[j][1]);
            acc[j][2] = fmaf(xv.z, wv, acc[j][2]);
            acc[j][3] = fmaf(xv.w, wv, acc[j][3]);
        }
    }
    #pragma unroll 4
    for (int c = 0; c < 128; ++c) {
        const float4 xv = *(const float4*)(kp + c * 4096);
        #pragma unroll
        for (int j = 0; j < 16; ++j) {
            float wv = w1q[j * 256 + 128 + c];
            acc[j][0] = fmaf(xv.x, wv, acc[j][0]);
            acc[j][1] = fmaf(xv.y, wv, acc[j][1]);
            acc[j][2] = fmaf(xv.z, wv, acc[j][2]);
            acc[j][3] = fmaf(xv.w, wv, acc[j][3]);
        }
    }

    __shared__ __align__(16) unsigned short e_s[64][256];   // bf16 bits, 32 KB
    #pragma unroll
    for (int j = 0; j < 16; ++j) {
        int eo = q * 16 + j;
        float s = eg[eo] * rsqrtf(ev[eo] + EPSV);
        float t = eb[eo] - em[eo] * s;
        float r0 = fmaxf(fmaf(acc[j][0], s, t), 0.f);
        float r1 = fmaxf(fmaf(acc[j][1], s, t), 0.f);
        float r2 = fmaxf(fmaf(acc[j][2], s, t), 0.f);
        float r3 = fmaxf(fmaf(acc[j][3], s, t), 0.f);
        uint2 pk;
        pk.x = bfbits(r0) | (bfbits(r1) << 16);
        pk.y = bfbits(r2) | (bfbits(r3) << 16);
        *(uint2*)&e_s[eo][pxl] = pk;
    }
    __syncthreads();

    float wa[24][4];
    #pragma unroll
    for (int j = 0; j < 24; ++j) {
        float b = be2[q * 24 + j];
        wa[j][0] = wa[j][1] = wa[j][2] = wa[j][3] = b;
    }
    const float* w2q = we2 + q * 24 * 64;
    #pragma unroll 4
    for (int c = 0; c < 64; ++c) {
        const uint2 eu = *(const uint2*)&e_s[c][pxl];
        float e0 = __uint_as_float(eu.x << 16);
        float e1 = __uint_as_float(eu.x & 0xffff0000u);
        float e2 = __uint_as_float(eu.y << 16);
        float e3 = __uint_as_float(eu.y & 0xffff0000u);
        #pragma unroll
        for (int j = 0; j < 24; ++j) {
            float wv = w2q[j * 64 + c];
            wa[j][0] = fmaf(e0, wv, wa[j][0]);
            wa[j][1] = fmaf(e1, wv, wa[j][1]);
            wa[j][2] = fmaf(e2, wv, wa[j][2]);
            wa[j][3] = fmaf(e3, wv, wa[j][3]);
        }
    }

    float* wdp = wd + (b2 * 96 + q * 24) * 4096 + px0;
    #pragma unroll
    for (int j = 0; j < 24; ++j) {
        float4 r; r.x = wa[j][0]; r.y = wa[j][1]; r.z = wa[j][2]; r.w = wa[j][3];
        *(float4*)(wdp + j * 4096) = r;
    }

    #pragma unroll
    for (int jj = 0; jj < 8; ++jj) {
        float lsum = 0.f, lsq = 0.f;
        #pragma unroll
        for (int k = 0; k < 3; ++k)
            #pragma unroll
            for (int p = 0; p < 4; ++p) {
                float vv = wa[jj * 3 + k][p];
                lsum += vv; lsq += vv * vv;
            }
        #pragma unroll
        for (int off = 32; off; off >>= 1) {
            lsum += __shfl_down(lsum, off, 64);
            lsq  += __shfl_down(lsq,  off, 64);
        }
        if (lane == 0) {
            atomicAdd(&gnsum[b2 * 32 + q * 8 + jj], lsum);
            atomicAdd(&gnsq [b2 * 32 + q * 8 + jj], lsq);
        }
    }
}

// ---- kC2: finalize GroupNorm stats ----
__global__ __launch_bounds__(256) void kC2_gn(
    const float* __restrict__ gnsum, const float* __restrict__ gnsq,
    float* __restrict__ gnmean, float* __restrict__ gnrstd)
{
    int idx = blockIdx.x * 256 + threadIdx.x;
    const float inv = 1.f / 12288.f;
    float mu  = gnsum[idx] * inv;
    float var = fmaf(gnsq[idx], inv, -mu * mu);
    gnmean[idx] = mu;
    gnrstd[idx] = rsqrtf(fmaxf(var, 0.f) + EPSV);
}

// ---- kD: agg = SiLU(BN2(sum_k GN(wd)*unfold(v))) -> d_out, + gap; thread = 4 px ----
__global__ __launch_bounds__(256, 8) void kD_agg(
    const float* __restrict__ wd, const float* __restrict__ v,
    const float* __restrict__ gnmean, const float* __restrict__ gnrstd,
    const float* __restrict__ gng, const float* __restrict__ gnb,
    const float* __restrict__ g, const float* __restrict__ bb,
    const float* __restrict__ m, const float* __restrict__ vr,
    float* __restrict__ out, float* __restrict__ gap)
{
    int blk   = blockIdx.x;
    int strip = blk & 3;
    int c     = (blk >> 2) & 127;
    int b2    = blk >> 9;
    int px0   = strip * 1024 + threadIdx.x * 4;
    int bi = b2 >> 3, ni = b2 & 7;
    int c1 = c >> 2;
    float mu = gnmean[b2 * 32 + c1], rs = gnrstd[b2 * 32 + c1];

    float a0 = 0.f, a1 = 0.f, a2 = 0.f, a3 = 0.f;
    #pragma unroll
    for (int k = 0; k < 3; ++k) {
        int nf = ni + k - 1;
        if (nf >= 0 && nf < 8) {
            int wo = c1 * 3 + k;
            float gg = gng[wo], gb = gnb[wo];
            const float4 wv = *(const float4*)(wd + (b2 * 96 + wo) * 4096 + px0);
            const float4 vv = *(const float4*)(v + ((bi * 8 + nf) * 128 + c) * 4096 + px0);
            a0 = fmaf(fmaf((wv.x - mu) * rs, gg, gb), vv.x, a0);
            a1 = fmaf(fmaf((wv.y - mu) * rs, gg, gb), vv.y, a1);
            a2 = fmaf(fmaf((wv.z - mu) * rs, gg, gb), vv.z, a2);
            a3 = fmaf(fmaf((wv.w - mu) * rs, gg, gb), vv.w, a3);
        }
    }
    float s = g[c] * rsqrtf(vr[c] + EPSV);
    float t = bb[c] - m[c] * s;
    float4 r;
    float y;
    y = fmaf(a0, s, t); r.x = y / (1.f + __expf(-y));
    y = fmaf(a1, s, t); r.y = y / (1.f + __expf(-y));
    y = fmaf(a2, s, t); r.z = y / (1.f + __expf(-y));
    y = fmaf(a3, s, t); r.w = y / (1.f + __expf(-y));
    *(float4*)(out + (b2 * 128 + c) * 4096 + px0) = r;
    block_sum_atomic(r.x + r.y + r.z + r.w, &gap[bi * 128 + c]);
}

// ---- kE1: a = ReLU(BNvec(gap/32768 @ w1^T + b1)) ----
__global__ __launch_bounds__(256) void kE1_a(
    const float* __restrict__ gap,
    const float* __restrict__ w1, const float* __restrict__ b1,
    const float* __restrict__ g, const float* __restrict__ bb,
    const float* __restrict__ m, const float* __restrict__ vr,
    float* __restrict__ a_buf)
{
    int idx = blockIdx.x * 256 + threadIdx.x;
    int bi = idx >> 7, oc = idx & 127;
    float acc = b1[oc];
    const float* gp = gap + bi * 128;
    const float* wp = w1 + oc * 128;
    for (int c = 0; c < 128; c += 4) {
        const float4 w4 = *(const float4*)(wp + c);
        acc = fmaf(gp[c + 0] * (1.f / 32768.f), w4.x, acc);
        acc = fmaf(gp[c + 1] * (1.f / 32768.f), w4.y, acc);
        acc = fmaf(gp[c + 2] * (1.f / 32768.f), w4.z, acc);
        acc = fmaf(gp[c + 3] * (1.f / 32768.f), w4.w, acc);
    }
    float s = g[oc] * rsqrtf(vr[oc] + EPSV);
    a_buf[bi * 128 + oc] = fmaxf(fmaf(acc, s, bb[oc] - m[oc] * s), 0.f);
}

// ---- kE2: attn = softmax over radix-2 pairs ----
__global__ __launch_bounds__(256) void kE2_attn(
    const float* __restrict__ a_buf,
    const float* __restrict__ w2, const float* __restrict__ b2v,
    float* __restrict__ attn)
{
    int idx = blockIdx.x * 256 + threadIdx.x;
    int bi = idx >> 7, cc = idx & 127;
    float l0 = b2v[cc * 2], l1 = b2v[cc * 2 + 1];
    const float* ap  = a_buf + bi * 128;
    const float* w0p = w2 + (cc * 2) * 128;
    const float* w1p = w2 + (cc * 2 + 1) * 128;
    for (int j = 0; j < 128; j += 4) {
        const float4 wa4 = *(const float4*)(w0p + j);
        const float4 wb4 = *(const float4*)(w1p + j);
        l0 = fmaf(ap[j + 0], wa4.x, l0); l1 = fmaf(ap[j + 0], wb4.x, l1);
        l0 = fmaf(ap[j + 1], wa4.y, l0); l1 = fmaf(ap[j + 1], wb4.y, l1);
        l0 = fmaf(ap[j + 2], wa4.z, l0); l1 = fmaf(ap[j + 2], wb4.z, l1);
        l0 = fmaf(ap[j + 3], wa4.w, l0); l1 = fmaf(ap[j + 3], wb4.w, l1);
    }
    float mx = fmaxf(l0, l1);
    float e0 = __expf(l0 - mx), e1 = __expf(l1 - mx);
    float inv = 1.f / (e0 + e1);
    attn[bi * 256 + cc * 2]     = e0 * inv;
    attn[bi * 256 + cc * 2 + 1] = e1 * inv;
}

// ---- kF: out = attn0*agg + attn1*k2d; thread = 4 px ----
__global__ __launch_bounds__(256, 8) void kF_out(
    float* __restrict__ out, const float* __restrict__ k2d,
    const float* __restrict__ attn)
{
    int blk   = blockIdx.x;
    int strip = blk & 3;
    int c     = (blk >> 2) & 127;
    int b2    = blk >> 9;
    int bi    = b2 >> 3;
    float a0 = attn[bi * 256 + c * 2];
    float a1 = attn[bi * 256 + c * 2 + 1];
    int idx = (b2 * 128 + c) * 4096 + strip * 1024 + threadIdx.x * 4;
    float4 o4 = *(const float4*)(out + idx);
    float4 k4 = *(const float4*)(k2d + idx);
    float4 r;
    r.x = fmaf(a0, o4.x, a1 * k4.x);
    r.y = fmaf(a0, o4.y, a1 * k4.y);
    r.z = fmaf(a0, o4.z, a1 * k4.z);
    r.w = fmaf(a0, o4.w, a1 * k4.w);
    *(float4*)(out + idx) = r;
}

extern "C" void kernel_launch(void* const* d_in, const int* in_sizes, int n_in,
                              void* d_out, int out_size, void* d_ws, size_t ws_size,
                              hipStream_t stream)
{
    const float* x      = (const float*)d_in[0];
    const float* w_key  = (const float*)d_in[1];
    const float* bnk_g  = (const float*)d_in[2];
    const float* bnk_b  = (const float*)d_in[3];
    const float* bnk_m  = (const float*)d_in[4];
    const float* bnk_v  = (const float*)d_in[5];
    const float* w_e1   = (const float*)d_in[6];
    const float* bne_g  = (const float*)d_in[7];
    const float* bne_b  = (const float*)d_in[8];
    const float* bne_m  = (const float*)d_in[9];
    const float* bne_v  = (const float*)d_in[10];
    const float* w_e2   = (const float*)d_in[11];
    const float* b_e2   = (const float*)d_in[12];
    const float* gn_g   = (const float*)d_in[13];
    const float* gn_b   = (const float*)d_in[14];
    const float* w_1x1  = (const float*)d_in[15];
    const float* bn1_g  = (const float*)d_in[16];
    const float* bn1_b  = (const float*)d_in[17];
    const float* bn1_m  = (const float*)d_in[18];
    const float* bn1_v  = (const float*)d_in[19];
    const float* bn2_g  = (const float*)d_in[20];
    const float* bn2_b  = (const float*)d_in[21];
    const float* bn2_m  = (const float*)d_in[22];
    const float* bn2_v  = (const float*)d_in[23];
    const float* w_se1  = (const float*)d_in[24];
    const float* b_se1  = (const float*)d_in[25];
    const float* bnse_g = (const float*)d_in[26];
    const float* bnse_b = (const float*)d_in[27];
    const float* bnse_m = (const float*)d_in[28];
    const float* bnse_v = (const float*)d_in[29];
    const float* w_se2  = (const float*)d_in[30];
    const float* b_se2  = (const float*)d_in[31];

    float* ws    = (float*)d_ws;
    float* k2d   = ws;
    float* v     = ws + 16777216;
    float* wd    = ws + 33554432;
    float* st    = ws + 46137344;
    float* gnsum  = st;
    float* gnsq   = st + 1024;
    float* gap    = st + 2048;
    float* gnmean = st + 2560;
    float* gnrstd = st + 3584;
    float* attn   = st + 4608;
    float* a_buf  = st;            // aliases gnsum (dead after kC2)

    hipMemsetAsync(gnsum, 0, 2560 * sizeof(float), stream);

    kA_key<<<1024, 256, 0, stream>>>(x, w_key, bnk_g, bnk_b, bnk_m, bnk_v, k2d, gap);
    kB_val<<<1024, 256, 0, stream>>>(x, w_1x1, bn1_g, bn1_b, bn1_m, bn1_v, v);
    kC_wd<<<512, 256, 0, stream>>>(x, k2d, w_e1, bne_g, bne_b, bne_m, bne_v,
                                   w_e2, b_e2, wd, gnsum, gnsq);
    kC2_gn<<<4, 256, 0, stream>>>(gnsum, gnsq, gnmean, gnrstd);
    kD_agg<<<16384, 256, 0, stream>>>(wd, v, gnmean, gnrstd, gn_g, gn_b,
                                      bn2_g, bn2_b, bn2_m, bn2_v,
                                      (float*)d_out, gap);
    kE1_a<<<2, 256, 0, stream>>>(gap, w_se1, b_se1, bnse_g, bnse_b, bnse_m, bnse_v, a_buf);
    kE2_attn<<<2, 256, 0, stream>>>(a_buf, w_se2, b_se2, attn);
    kF_out<<<16384, 256, 0, stream>>>((float*)d_out, k2d, attn);
}